// Round 3
// baseline (293.237 us; speedup 1.0000x reference)
//
#include <hip/hip_runtime.h>

// Problem constants (fixed by setup_inputs): N=64, L=256, C=384.
#define N_B    64
#define L_IN   256
#define C_DIM  384
#define C4     (C_DIM / 4)      // 96 float4 per row
#define F4_PER_BLOCK 2048       // 8 iterations x 256 threads, 32 KB stored/block
#define ITERS  (F4_PER_BLOCK / 256)

// clang-native 4-float vector.
typedef float vfloat4 __attribute__((ext_vector_type(4)));

// CALIBRATION ROUND: the fused kernel below is unchanged from R1 and fully
// idempotent. kernel_launch dispatches it TWICE back-to-back; the dur_us
// delta vs R1 directly measures the kernel's standalone duration (output
// traffic is 232 MB/pass, 7x the 32 MB aggregate L2, so pass 2 cannot
// complete in-cache). This resolves whether the gather is at its ~40 us
// traffic roofline (remaining gap = harness overhead) or has ~2x headroom.
__global__ __launch_bounds__(256) void lr_fused_kernel(const vfloat4* __restrict__ x,
                                                       const int* __restrict__ dur,
                                                       vfloat4* __restrict__ out,
                                                       float* __restrict__ melpos,
                                                       int melmax, int chunks_per_n) {
    __shared__ int sbuf[2][L_IN];   // double-buffered scan (2 KB)
    __shared__ int r_tab[32];       // tcnt <= 2048/96 + 1 = 23

    const int j      = (int)blockIdx.x;
    const int xcd    = j & 7;               // dispatch round-robins XCDs
    const int s      = j >> 3;
    const int n      = xcd + 8 * (s / chunks_per_n);
    const int bchunk = s % chunks_per_n;
    const int tid    = (int)threadIdx.x;

    const int row_f4 = melmax * C4;
    const int start  = bchunk * F4_PER_BLOCK;
    if (start >= row_f4) return;
    const bool full  = (start + F4_PER_BLOCK) <= row_f4;
    const int end    = full ? (start + F4_PER_BLOCK) : row_f4;

    // --- 1+2: load durations, inclusive scan (double-buffered, 8 barriers) ---
    sbuf[0][tid] = dur[n * L_IN + tid];
    __syncthreads();
    int p = 0;
    #pragma unroll
    for (int off = 1; off < L_IN; off <<= 1) {
        int vsum = sbuf[p][tid] + ((tid >= off) ? sbuf[p][tid - off] : 0);
        sbuf[p ^ 1][tid] = vsum;
        p ^= 1;
        __syncthreads();
    }
    const int* csum = sbuf[p];
    const int total = csum[L_IN - 1];

    // --- 3: r values for this chunk's t-range (+ melpos slice from n==0) ---
    const int t0   = start / C4;
    const int tcnt = (end - 1) / C4 - t0 + 1;
    if (tid < tcnt) {
        const int t = t0 + tid;
        int r = -1;
        if (t < total) {
            int lo = 0, hi = L_IN;
            #pragma unroll
            for (int q = 0; q < 8; ++q) {   // log2(256)
                int mid = (lo + hi) >> 1;
                if (csum[mid] <= t) lo = mid + 1; else hi = mid;
            }
            r = (lo < (L_IN - 1)) ? lo : (L_IN - 1);
        }
        r_tab[tid] = r;
        if (n == 0) melpos[t] = (float)(t + 1);   // mel_pos = arange(1, melmax+1)
    }
    __syncthreads();

    // --- 4: stream the chunk ---
    const size_t obase = (size_t)n * row_f4;
    if (full) {
        vfloat4 v[ITERS];
        #pragma unroll
        for (int i = 0; i < ITERS; ++i) {
            const int off = start + tid + 256 * i;
            const int t   = off / C4;            // const divisor -> mul/shift
            const int c4  = off - t * C4;
            const int r   = r_tab[t - t0];
            const int rc  = (r >= 0) ? r : 0;    // unconditional load; select after
            vfloat4 tmp = x[(n * L_IN + rc) * C4 + c4];
            v[i] = (r >= 0) ? tmp : (vfloat4)0.f;
        }
        #pragma unroll
        for (int i = 0; i < ITERS; ++i) {
            out[obase + start + tid + 256 * i] = v[i];
        }
    } else {
        for (int off = start + tid; off < end; off += 256) {
            const int t  = off / C4;
            const int c4 = off - t * C4;
            const int r  = r_tab[t - t0];
            vfloat4 v = (vfloat4)0.f;
            if (r >= 0) v = x[(n * L_IN + r) * C4 + c4];
            out[obase + off] = v;
        }
    }
}

extern "C" void kernel_launch(void* const* d_in, const int* in_sizes, int n_in,
                              void* d_out, int out_size, void* d_ws, size_t ws_size,
                              hipStream_t stream) {
    const float* x  = (const float*)d_in[0];
    const int* dur  = (const int*)d_in[1];
    // d_in[2] (mel_max_length) is device-resident; derive on host:
    // out_size = N*mel*C + mel = mel * (N*C + 1)
    const int melmax = out_size / (N_B * C_DIM + 1);

    float* mp = (float*)d_out + (size_t)N_B * melmax * C_DIM; // mel_pos

    const int row_f4 = melmax * C4;
    const int chunks_per_n = (row_f4 + F4_PER_BLOCK - 1) / F4_PER_BLOCK;

    // CALIBRATION: two identical, idempotent dispatches. dur_us delta vs R1
    // == standalone kernel duration (+ ~3 us launch gap).
    lr_fused_kernel<<<chunks_per_n * N_B, 256, 0, stream>>>(
        (const vfloat4*)x, dur, (vfloat4*)d_out, mp, melmax, chunks_per_n);
    lr_fused_kernel<<<chunks_per_n * N_B, 256, 0, stream>>>(
        (const vfloat4*)x, dur, (vfloat4*)d_out, mp, melmax, chunks_per_n);
}

// Round 4
// 251.427 us; speedup vs baseline: 1.1663x; 1.1663x over previous
//
#include <hip/hip_runtime.h>

// Problem constants (fixed by setup_inputs): N=64, L=256, C=384.
#define N_B    64
#define L_IN   256
#define C_DIM  384
#define C4     (C_DIM / 4)      // 96 float4 per row
#define F4_PER_BLOCK 2048       // 8 iterations x 256 threads, 32 KB stored/block
#define ITERS  (F4_PER_BLOCK / 256)

// clang-native 4-float vector.
typedef float vfloat4 __attribute__((ext_vector_type(4)));

// Final kernel (revert of the R2 calibration double-launch; logic == R1).
//
// Roofline accounting (measured, R2 calibration): standalone kernel duration
// ~41 us == (232 MB compulsory write + ~25 MB read) / 6.4 TB/s achievable —
// same ~81%-of-peak HBM rate the harness fill kernel reaches. The remaining
// dur_us is the harness's 928 MB re-poison fill (~144 us) + reset-dispatch
// overhead, both outside kernel_launch's control.
//
// Each block:
//   1. loads its batch's 256 durations (1 KB, L2-resident after first touch),
//   2. 8-round double-buffered Hillis-Steele scan in LDS (1 barrier/round),
//   3. binary-searches the <=23 t values its chunk covers -> r_tab,
//   4. streams 32 KB: unrolled 8x float4 load / 8x store.
// Block ordering is chunk-major within an XCD: XCD k streams batch k, then
// k+8, ... so its live x working set (~384 KB) stays L2-resident.
__global__ __launch_bounds__(256) void lr_fused_kernel(const vfloat4* __restrict__ x,
                                                       const int* __restrict__ dur,
                                                       vfloat4* __restrict__ out,
                                                       float* __restrict__ melpos,
                                                       int melmax, int chunks_per_n) {
    __shared__ int sbuf[2][L_IN];   // double-buffered scan (2 KB)
    __shared__ int r_tab[32];       // tcnt <= 2048/96 + 1 = 23

    const int j      = (int)blockIdx.x;
    const int xcd    = j & 7;               // dispatch round-robins XCDs
    const int s      = j >> 3;
    const int n      = xcd + 8 * (s / chunks_per_n);
    const int bchunk = s % chunks_per_n;
    const int tid    = (int)threadIdx.x;

    const int row_f4 = melmax * C4;
    const int start  = bchunk * F4_PER_BLOCK;
    if (start >= row_f4) return;
    const bool full  = (start + F4_PER_BLOCK) <= row_f4;
    const int end    = full ? (start + F4_PER_BLOCK) : row_f4;

    // --- 1+2: load durations, inclusive scan (double-buffered, 8 barriers) ---
    sbuf[0][tid] = dur[n * L_IN + tid];
    __syncthreads();
    int p = 0;
    #pragma unroll
    for (int off = 1; off < L_IN; off <<= 1) {
        int vsum = sbuf[p][tid] + ((tid >= off) ? sbuf[p][tid - off] : 0);
        sbuf[p ^ 1][tid] = vsum;
        p ^= 1;
        __syncthreads();
    }
    const int* csum = sbuf[p];
    const int total = csum[L_IN - 1];

    // --- 3: r values for this chunk's t-range (+ melpos slice from n==0) ---
    const int t0   = start / C4;
    const int tcnt = (end - 1) / C4 - t0 + 1;
    if (tid < tcnt) {
        const int t = t0 + tid;
        int r = -1;
        if (t < total) {
            int lo = 0, hi = L_IN;
            #pragma unroll
            for (int q = 0; q < 8; ++q) {   // log2(256)
                int mid = (lo + hi) >> 1;
                if (csum[mid] <= t) lo = mid + 1; else hi = mid;
            }
            r = (lo < (L_IN - 1)) ? lo : (L_IN - 1);
        }
        r_tab[tid] = r;
        if (n == 0) melpos[t] = (float)(t + 1);   // mel_pos = arange(1, melmax+1)
    }
    __syncthreads();

    // --- 4: stream the chunk ---
    const size_t obase = (size_t)n * row_f4;
    if (full) {
        vfloat4 v[ITERS];
        #pragma unroll
        for (int i = 0; i < ITERS; ++i) {
            const int off = start + tid + 256 * i;
            const int t   = off / C4;            // const divisor -> mul/shift
            const int c4  = off - t * C4;
            const int r   = r_tab[t - t0];
            const int rc  = (r >= 0) ? r : 0;    // unconditional load; select after
            vfloat4 tmp = x[(n * L_IN + rc) * C4 + c4];
            v[i] = (r >= 0) ? tmp : (vfloat4)0.f;
        }
        #pragma unroll
        for (int i = 0; i < ITERS; ++i) {
            out[obase + start + tid + 256 * i] = v[i];
        }
    } else {
        for (int off = start + tid; off < end; off += 256) {
            const int t  = off / C4;
            const int c4 = off - t * C4;
            const int r  = r_tab[t - t0];
            vfloat4 v = (vfloat4)0.f;
            if (r >= 0) v = x[(n * L_IN + r) * C4 + c4];
            out[obase + off] = v;
        }
    }
}

extern "C" void kernel_launch(void* const* d_in, const int* in_sizes, int n_in,
                              void* d_out, int out_size, void* d_ws, size_t ws_size,
                              hipStream_t stream) {
    const float* x  = (const float*)d_in[0];
    const int* dur  = (const int*)d_in[1];
    // d_in[2] (mel_max_length) is device-resident; derive on host:
    // out_size = N*mel*C + mel = mel * (N*C + 1)
    const int melmax = out_size / (N_B * C_DIM + 1);

    float* mp = (float*)d_out + (size_t)N_B * melmax * C_DIM; // mel_pos

    const int row_f4 = melmax * C4;
    const int chunks_per_n = (row_f4 + F4_PER_BLOCK - 1) / F4_PER_BLOCK;
    lr_fused_kernel<<<chunks_per_n * N_B, 256, 0, stream>>>(
        (const vfloat4*)x, dur, (vfloat4*)d_out, mp, melmax, chunks_per_n);
}